// Round 4
// baseline (198.684 us; speedup 1.0000x reference)
//
#include <hip/hip_runtime.h>
#include <math.h>

#define NB 2
#define NL 256
#define DM 512
#define NH 8
#define DQ 64

typedef float v2f __attribute__((ext_vector_type(2)));

#if __has_builtin(__builtin_elementwise_fma)
__device__ __forceinline__ v2f fmav(v2f a, v2f b, v2f c) {
    return __builtin_elementwise_fma(a, b, c);
}
#else
__device__ __forceinline__ v2f fmav(v2f a, v2f b, v2f c) {
    v2f r; r.x = fmaf(a.x, b.x, c.x); r.y = fmaf(a.y, b.y, c.y); return r;
}
#endif
__device__ __forceinline__ v2f swapv(v2f a) {
    return __builtin_shufflevector(a, a, 1, 0);
}

// ---------------------------------------------------------------------------
// K1: QKV projection GEMM (R16-passed, unchanged). Register double-buffered.
// z==1 (k): TRANSPOSED (b,h,d,t). z==2 (v): computes u = (v+bias)@Win_h.
// ---------------------------------------------------------------------------
__global__ __launch_bounds__(256) void qkv_gemm(
    const float* __restrict__ xq, const float* __restrict__ xk,
    const float* __restrict__ xv,
    const float* __restrict__ Wq, const float* __restrict__ Wk,
    const float* __restrict__ Wv,
    const float* __restrict__ bq, const float* __restrict__ bk,
    const float* __restrict__ bv,
    const float* __restrict__ Wre, const float* __restrict__ Wim,
    float* __restrict__ q, float* __restrict__ kT, float2* __restrict__ u)
{
    int z = blockIdx.z;
    const float* X = (z == 0) ? xq : (z == 1) ? xk : xv;
    const float* W = (z == 0) ? Wq : (z == 1) ? Wk : Wv;
    const float* bias = (z == 0) ? bq : (z == 1) ? bk : bv;

    __shared__ float As[32][33];
    __shared__ float Bs[32][68];

    int tid = threadIdx.x;
    int tx = tid & 15, ty = tid >> 4;
    int m0 = blockIdx.y * 32, n0 = blockIdx.x * 64;

    int ar = tid >> 3, ac4 = (tid & 7) * 4;
    int br = tid >> 4, bc4 = (tid & 15) * 4;
    const float* Aptr = X + (m0 + ar) * 512 + ac4;
    const float* Bptr0 = W + br * 512 + n0 + bc4;
    const float* Bptr1 = W + (br + 16) * 512 + n0 + bc4;

    float acc[2][4] = {};

    float4 aR = *(const float4*)(Aptr);
    float4 bR0 = *(const float4*)(Bptr0);
    float4 bR1 = *(const float4*)(Bptr1);

    for (int k0 = 0; k0 < 512; k0 += 32) {
        As[ac4 + 0][ar] = aR.x; As[ac4 + 1][ar] = aR.y;
        As[ac4 + 2][ar] = aR.z; As[ac4 + 3][ar] = aR.w;
        *(float4*)&Bs[br][bc4] = bR0;
        *(float4*)&Bs[br + 16][bc4] = bR1;
        __syncthreads();

        if (k0 + 32 < 512) {
            aR  = *(const float4*)(Aptr + k0 + 32);
            bR0 = *(const float4*)(Bptr0 + (k0 + 32) * 512);
            bR1 = *(const float4*)(Bptr1 + (k0 + 32) * 512);
        }

        #pragma unroll
        for (int kk = 0; kk < 32; kk++) {
            float a0 = As[kk][ty * 2 + 0];
            float a1 = As[kk][ty * 2 + 1];
            float4 bb = *(const float4*)&Bs[kk][tx * 4];
            acc[0][0] += a0 * bb.x; acc[0][1] += a0 * bb.y;
            acc[0][2] += a0 * bb.z; acc[0][3] += a0 * bb.w;
            acc[1][0] += a1 * bb.x; acc[1][1] += a1 * bb.y;
            acc[1][2] += a1 * bb.z; acc[1][3] += a1 * bb.w;
        }
        __syncthreads();
    }

    if (z < 2) {
        float* O = (z == 0) ? q : kT;
        #pragma unroll
        for (int i = 0; i < 2; i++) {
            int m = m0 + ty * 2 + i;
            int b = m >> 8, l = m & 255;
            #pragma unroll
            for (int j = 0; j < 4; j++) {
                int n = n0 + tx * 4 + j;
                int h = n >> 6, d = n & 63;
                float val = acc[i][j] + bias[n];
                if (z == 1)
                    O[((b * NH + h) * DQ + d) * NL + l] = val;   // kT
                else
                    O[((b * NH + h) * NL + l) * DQ + d] = val;
            }
        }
    } else {
        int h = blockIdx.x;            // n-tile == head
        int b = m0 >> 8;
        #pragma unroll
        for (int i = 0; i < 2; i++)
            #pragma unroll
            for (int j = 0; j < 4; j++)
                Bs[ty * 2 + i][tx * 4 + j] = acc[i][j] + bias[n0 + tx * 4 + j];
        __syncthreads();

        int r0 = ty * 2, c4 = tx * 4;
        float ur[2][4] = {}, ui[2][4] = {};
        const float* wr = Wre + h * 4096 + c4;
        const float* wi = Wim + h * 4096 + c4;
        #pragma unroll 4
        for (int d = 0; d < 64; d++) {
            float v0 = Bs[r0][d];
            float v1 = Bs[r0 + 1][d];
            float4 wre = *(const float4*)(wr + d * 64);
            float4 wim = *(const float4*)(wi + d * 64);
            ur[0][0] += v0 * wre.x; ur[0][1] += v0 * wre.y;
            ur[0][2] += v0 * wre.z; ur[0][3] += v0 * wre.w;
            ui[0][0] += v0 * wim.x; ui[0][1] += v0 * wim.y;
            ui[0][2] += v0 * wim.z; ui[0][3] += v0 * wim.w;
            ur[1][0] += v1 * wre.x; ur[1][1] += v1 * wre.y;
            ur[1][2] += v1 * wre.z; ur[1][3] += v1 * wre.w;
            ui[1][0] += v1 * wim.x; ui[1][1] += v1 * wim.y;
            ui[1][2] += v1 * wim.z; ui[1][3] += v1 * wim.w;
        }
        #pragma unroll
        for (int i = 0; i < 2; i++) {
            int l = (m0 & 255) + r0 + i;
            float2* up = u + ((size_t)(b * NH + h) * NL + l) * DQ + c4;
            #pragma unroll
            for (int j = 0; j < 4; j++)
                up[j] = make_float2(ur[i][j], ui[i][j]);
        }
    }
}

// ---------------------------------------------------------------------------
// K2a: attention prologue (QK^T + softmax), split out this round.
// Shape = R2's verified prologue: 1024 blocks x 64 thr, 4 q-rows per wave
// (amortizes the 64KB kT slice over 4 rows -> 64MB total L2 traffic).
// Numerics verbatim from the R2/R3-passed kernels.
// ---------------------------------------------------------------------------
__global__ __launch_bounds__(64) void attn_kernel(
    const float* __restrict__ q, const float* __restrict__ kT,
    const float* __restrict__ mask, float* __restrict__ attn_o)
{
    int lane = threadIdx.x;       // block = 1 wave
    int blk = blockIdx.x;         // 1024: b(1) | h(3) | qg(6)
    int qg = blk & 63;            // group of 4 q rows
    int h  = (blk >> 6) & 7;
    int b  = blk >> 9;

    __shared__ float qs[4][68];

    {
        const float4* qsrc = (const float4*)(q + ((size_t)(b * NH + h) * NL + qg * 4) * DQ);
        float4 f4 = qsrc[lane];
        *(float4*)&qs[lane >> 4][(lane & 15) * 4] = f4;
    }
    __syncthreads();

    const float* kp = kT + (size_t)((b * NH + h) * DQ) * NL + lane;
    float acc[4][4] = {};
    #pragma unroll
    for (int d4 = 0; d4 < 16; d4++) {
        float kv[4][4];
        #pragma unroll
        for (int kk = 0; kk < 4; kk++)
            #pragma unroll
            for (int i = 0; i < 4; i++)
                kv[kk][i] = kp[(size_t)(d4 * 4 + i) * NL + kk * 64];
        #pragma unroll
        for (int r = 0; r < 4; r++) {
            float4 qv = *(const float4*)&qs[r][d4 * 4];
            #pragma unroll
            for (int kk = 0; kk < 4; kk++)
                acc[r][kk] += qv.x * kv[kk][0] + qv.y * kv[kk][1]
                            + qv.z * kv[kk][2] + qv.w * kv[kk][3];
        }
    }
    float l[4][4];
    #pragma unroll
    for (int r = 0; r < 4; r++)
        #pragma unroll
        for (int kk = 0; kk < 4; kk++) {
            float mv = mask[(size_t)(b * NL + qg * 4 + r) * NL + lane + kk * 64];
            l[r][kk] = acc[r][kk] * 0.125f - ((mv == 1.0f) ? INFINITY : mv);
        }
    #pragma unroll
    for (int r = 0; r < 4; r++) {
        float mx = fmaxf(fmaxf(l[r][0], l[r][1]), fmaxf(l[r][2], l[r][3]));
        #pragma unroll
        for (int o = 32; o; o >>= 1) mx = fmaxf(mx, __shfl_xor(mx, o, 64));
        float s = __expf(l[r][0] - mx) + __expf(l[r][1] - mx)
                + __expf(l[r][2] - mx) + __expf(l[r][3] - mx);
        #pragma unroll
        for (int o = 32; o; o >>= 1) s += __shfl_xor(s, o, 64);
        float rs = __builtin_amdgcn_rcpf(s);
        #pragma unroll
        for (int kk = 0; kk < 4; kk++) {
            float pv = __expf(l[r][kk] - mx) * rs;
            attn_o[((size_t)(b * NH + h) * NL + qg * 4 + r) * NL + lane + kk * 64] = pv;
        }
    }
}

// ---------------------------------------------------------------------------
// K2b: EUNN recurrence only. 1 complex dim per lane (R1-passed math body,
// verbatim), 1 row per wave, 4 waves/block, 1024 blocks x 256 thr
// = 16 waves/CU = 4 waves/SIMD. No LDS, no barriers.
//   - a_t: wave-uniform loads from attn_o (scalar-load eligible; zero
//     VALU/LDS cost in the chain)
//   - u: register double-buffered in 8-step groups; __launch_bounds__(256,4)
//     caps VGPR at 128 (est. live ~80) so the buffers STAY in registers
//     (R1-R3's demotion theory: launch_bounds(64) let the backend squeeze
//     to 44 VGPRs, sinking loads into the serial chain -> ~600 cy/step).
// ---------------------------------------------------------------------------
__device__ __forceinline__ float dpp_swap1(float x) {  // lane i <- lane i^1
    return __int_as_float(__builtin_amdgcn_mov_dpp(__float_as_int(x), 0xB1, 0xF, 0xF, true));
}
__device__ __forceinline__ float dpp_rol1(float x) {   // lane i <- lane (i+1)%64
    return __int_as_float(__builtin_amdgcn_mov_dpp(__float_as_int(x), 0x134, 0xF, 0xF, true));
}
__device__ __forceinline__ float dpp_ror1(float x) {   // lane i <- lane (i-1)%64
    return __int_as_float(__builtin_amdgcn_mov_dpp(__float_as_int(x), 0x13C, 0xF, 0xF, true));
}

__device__ __forceinline__ v2f mdr(v2f z, float bv) {  // modrelu, exact reference form
    float mm = z.x * z.x + z.y * z.y;
    float m = __builtin_amdgcn_sqrtf(mm);
    float sc = fmaxf(m + bv, 0.f) * __builtin_amdgcn_rcpf(m + 1e-5f);
    v2f s = {sc, sc};
    return z * s;
}

__global__ __launch_bounds__(256, 4) void rnn_kernel(
    const float* __restrict__ attn, const float2* __restrict__ u,
    const float* __restrict__ theta, const float* __restrict__ phi,
    const float* __restrict__ rnn_bias, float* __restrict__ rnn_out)
{
    int tid  = threadIdx.x;
    int lane = tid & 63;          // complex dim
    int wv   = tid >> 6;          // wave = one q row
    int blk  = blockIdx.x;        // 1024: b(1) | h(3) | qg(6)
    int qg   = blk & 63;
    int h    = (blk >> 6) & 7;
    int b    = blk >> 9;
    int qi   = qg * 4 + wv;

    int d = lane;
    bool odd = d & 1;

    const float* tb = theta + h * 64;    // (8,2,32): c=0 at [0..31], c=1 at [32..63]
    const float* pb = phi + h * 64;

    // ---- coefficients: verbatim R1-passed ----
    int i0 = d >> 1;
    float th0 = tb[i0], ph0 = pb[i0];
    float c0 = cosf(th0), s0 = sinf(th0);
    float W0r = (odd ? s0 : -s0) * cosf(ph0);
    float W0i = -s0 * sinf(ph0);

    int i1 = odd ? (d >> 1) : (((d + 62) & 63) >> 1);
    float th1 = tb[32 + i1], ph1 = pb[32 + i1];
    float c1 = cosf(th1), s1 = sinf(th1);
    float W1r = (odd ? -s1 : s1) * cosf(ph1);
    float W1i = -s1 * sinf(ph1);

    float biasv = rnn_bias[h * 64 + d];

    v2f c0v = {c0, c0}, c1v = {c1, c1};
    v2f W0rV = {W0r, W0r}, W0iN = {-W0i, W0i};
    v2f W1rV = {W1r, W1r}, W1iN = {-W1i, W1i};

    const float* ar = attn + ((size_t)(b * NH + h) * NL + qi) * NL;   // wave-uniform
    const float2* up = u + (size_t)((b * NH + h) * NL) * DQ + d;      // coalesced

    v2f e = {0.f, 0.f};

    #define RSTEP(a_t, uu) do {                                              \
        v2f atv = {(a_t), (a_t)};                                            \
        v2f uv = {(uu).x, (uu).y};                                           \
        v2f p0;                                                              \
        p0.x = dpp_swap1(e.x); p0.y = dpp_swap1(e.y);                        \
        v2f g = fmav(c0v, e, fmav(W0rV, p0, W0iN * swapv(p0)));              \
        v2f rl, rr;                                                          \
        rl.x = dpp_rol1(g.x); rl.y = dpp_rol1(g.y);                          \
        rr.x = dpp_ror1(g.x); rr.y = dpp_ror1(g.y);                          \
        v2f p1;                                                              \
        p1.x = odd ? rl.x : rr.x;                                            \
        p1.y = odd ? rl.y : rr.y;                                            \
        v2f z = fmav(c1v, g, fmav(W1rV, p1, fmav(W1iN, swapv(p1), atv * uv))); \
        e = mdr(z, biasv);                                                   \
    } while (0)

    // register double-buffer: 8-step groups, loads never enter the chain
    float2 A0[8], A1[8];
    float  s0v[8], s1v[8];

    #pragma unroll
    for (int i = 0; i < 8; i++) A0[i] = up[i * 64];
    #pragma unroll
    for (int i = 0; i < 8; i++) s0v[i] = ar[i];

    for (int k = 0; k < 16; k++) {            // 16 steps per iteration
        int t1 = k * 16 + 8;
        #pragma unroll
        for (int i = 0; i < 8; i++) A1[i] = up[(t1 + i) * 64];
        #pragma unroll
        for (int i = 0; i < 8; i++) s1v[i] = ar[t1 + i];

        #pragma unroll
        for (int j = 0; j < 8; j++) RSTEP(s0v[j], A0[j]);

        if (k < 15) {
            int t2 = k * 16 + 16;
            #pragma unroll
            for (int i = 0; i < 8; i++) A0[i] = up[(t2 + i) * 64];
            #pragma unroll
            for (int i = 0; i < 8; i++) s0v[i] = ar[t2 + i];
        }

        #pragma unroll
        for (int j = 0; j < 8; j++) RSTEP(s1v[j], A1[j]);
    }
    #undef RSTEP

    rnn_out[(size_t)(b * NL + qi) * DM + h * DQ + d] = e.x;
}

// ---------------------------------------------------------------------------
// K3: output projection (R16-passed, unchanged). Register double-buffered.
// ---------------------------------------------------------------------------
__global__ __launch_bounds__(256) void out_gemm(
    const float* __restrict__ A, const float* __restrict__ W,
    const float* __restrict__ bias, float* __restrict__ C)
{
    __shared__ float As[32][17];
    __shared__ float Bs[32][68];

    int tid = threadIdx.x;
    int tx = tid & 15, ty = tid >> 4;
    int m0 = blockIdx.y * 16, n0 = blockIdx.x * 64;

    int ar = tid >> 4, ac2 = (tid & 15) * 2;
    int br = tid >> 4, bc4 = (tid & 15) * 4;
    const float* Aptr = A + (m0 + ar) * 512 + ac2;
    const float* Bptr0 = W + br * 512 + n0 + bc4;
    const float* Bptr1 = W + (br + 16) * 512 + n0 + bc4;

    float acc[4] = {};

    float2 aR = *(const float2*)(Aptr);
    float4 bR0 = *(const float4*)(Bptr0);
    float4 bR1 = *(const float4*)(Bptr1);

    for (int k0 = 0; k0 < 512; k0 += 32) {
        As[ac2 + 0][ar] = aR.x; As[ac2 + 1][ar] = aR.y;
        *(float4*)&Bs[br][bc4] = bR0;
        *(float4*)&Bs[br + 16][bc4] = bR1;
        __syncthreads();

        if (k0 + 32 < 512) {
            aR  = *(const float2*)(Aptr + k0 + 32);
            bR0 = *(const float4*)(Bptr0 + (k0 + 32) * 512);
            bR1 = *(const float4*)(Bptr1 + (k0 + 32) * 512);
        }

        #pragma unroll
        for (int kk = 0; kk < 32; kk++) {
            float a = As[kk][ty];
            float4 bb = *(const float4*)&Bs[kk][tx * 4];
            acc[0] += a * bb.x; acc[1] += a * bb.y;
            acc[2] += a * bb.z; acc[3] += a * bb.w;
        }
        __syncthreads();
    }

    int m = m0 + ty;
    #pragma unroll
    for (int j = 0; j < 4; j++) {
        int n = n0 + tx * 4 + j;
        C[m * 512 + n] = acc[j] + bias[n];
    }
}

// ---------------------------------------------------------------------------
extern "C" void kernel_launch(void* const* d_in, const int* in_sizes, int n_in,
                              void* d_out, int out_size, void* d_ws, size_t ws_size,
                              hipStream_t stream)
{
    const float* x_q  = (const float*)d_in[0];
    const float* x_k  = (const float*)d_in[1];
    const float* x_v  = (const float*)d_in[2];
    const float* mask = (const float*)d_in[3];
    const float* Wq   = (const float*)d_in[4];
    const float* bq   = (const float*)d_in[5];
    const float* Wk   = (const float*)d_in[6];
    const float* bk   = (const float*)d_in[7];
    const float* Wv   = (const float*)d_in[8];
    const float* bv   = (const float*)d_in[9];
    const float* Wo   = (const float*)d_in[10];
    const float* bo   = (const float*)d_in[11];
    const float* theta= (const float*)d_in[12];
    const float* phi  = (const float*)d_in[13];
    const float* Wre  = (const float*)d_in[14];
    const float* Wim  = (const float*)d_in[15];
    const float* rb   = (const float*)d_in[16];

    float* ws = (float*)d_ws;
    float*  q_ws    = ws;                       // 262144 f
    float*  kT_ws   = ws + 262144;              // 262144 f (b,h,d,t)
    float2* u_ws    = (float2*)(ws + 524288);   // 262144 float2
    float*  rnn_o   = ws + 1048576;             // 262144 f

    float* out_o  = (float*)d_out;              // (2,256,512)
    float* attn_o = out_o + NB * NL * DM;       // (2,8,256,256)

    qkv_gemm<<<dim3(8, 16, 3), 256, 0, stream>>>(
        x_q, x_k, x_v, Wq, Wk, Wv, bq, bk, bv, Wre, Wim,
        q_ws, kT_ws, u_ws);

    attn_kernel<<<dim3(1024), 64, 0, stream>>>(
        q_ws, kT_ws, mask, attn_o);

    rnn_kernel<<<dim3(1024), 256, 0, stream>>>(
        attn_o, u_ws, theta, phi, rb, rnn_o);

    out_gemm<<<dim3(8, 32), 256, 0, stream>>>(rnn_o, Wo, bo, out_o);
}

// Round 5
// 185.804 us; speedup vs baseline: 1.0693x; 1.0693x over previous
//
#include <hip/hip_runtime.h>
#include <math.h>

#define NB 2
#define NL 256
#define DM 512
#define NH 8
#define DQ 64

typedef float v2f __attribute__((ext_vector_type(2)));

#if __has_builtin(__builtin_elementwise_fma)
__device__ __forceinline__ v2f fmav(v2f a, v2f b, v2f c) {
    return __builtin_elementwise_fma(a, b, c);
}
#else
__device__ __forceinline__ v2f fmav(v2f a, v2f b, v2f c) {
    v2f r; r.x = fmaf(a.x, b.x, c.x); r.y = fmaf(a.y, b.y, c.y); return r;
}
#endif
__device__ __forceinline__ v2f swapv(v2f a) {
    return __builtin_shufflevector(a, a, 1, 0);
}

// ---------------------------------------------------------------------------
// K1: QKV projection GEMM (R16-passed, unchanged). Register double-buffered.
// z==1 (k): TRANSPOSED (b,h,d,t). z==2 (v): computes u = (v+bias)@Win_h.
// ---------------------------------------------------------------------------
__global__ __launch_bounds__(256) void qkv_gemm(
    const float* __restrict__ xq, const float* __restrict__ xk,
    const float* __restrict__ xv,
    const float* __restrict__ Wq, const float* __restrict__ Wk,
    const float* __restrict__ Wv,
    const float* __restrict__ bq, const float* __restrict__ bk,
    const float* __restrict__ bv,
    const float* __restrict__ Wre, const float* __restrict__ Wim,
    float* __restrict__ q, float* __restrict__ kT, float2* __restrict__ u)
{
    int z = blockIdx.z;
    const float* X = (z == 0) ? xq : (z == 1) ? xk : xv;
    const float* W = (z == 0) ? Wq : (z == 1) ? Wk : Wv;
    const float* bias = (z == 0) ? bq : (z == 1) ? bk : bv;

    __shared__ float As[32][33];
    __shared__ float Bs[32][68];

    int tid = threadIdx.x;
    int tx = tid & 15, ty = tid >> 4;
    int m0 = blockIdx.y * 32, n0 = blockIdx.x * 64;

    int ar = tid >> 3, ac4 = (tid & 7) * 4;
    int br = tid >> 4, bc4 = (tid & 15) * 4;
    const float* Aptr = X + (m0 + ar) * 512 + ac4;
    const float* Bptr0 = W + br * 512 + n0 + bc4;
    const float* Bptr1 = W + (br + 16) * 512 + n0 + bc4;

    float acc[2][4] = {};

    float4 aR = *(const float4*)(Aptr);
    float4 bR0 = *(const float4*)(Bptr0);
    float4 bR1 = *(const float4*)(Bptr1);

    for (int k0 = 0; k0 < 512; k0 += 32) {
        As[ac4 + 0][ar] = aR.x; As[ac4 + 1][ar] = aR.y;
        As[ac4 + 2][ar] = aR.z; As[ac4 + 3][ar] = aR.w;
        *(float4*)&Bs[br][bc4] = bR0;
        *(float4*)&Bs[br + 16][bc4] = bR1;
        __syncthreads();

        if (k0 + 32 < 512) {
            aR  = *(const float4*)(Aptr + k0 + 32);
            bR0 = *(const float4*)(Bptr0 + (k0 + 32) * 512);
            bR1 = *(const float4*)(Bptr1 + (k0 + 32) * 512);
        }

        #pragma unroll
        for (int kk = 0; kk < 32; kk++) {
            float a0 = As[kk][ty * 2 + 0];
            float a1 = As[kk][ty * 2 + 1];
            float4 bb = *(const float4*)&Bs[kk][tx * 4];
            acc[0][0] += a0 * bb.x; acc[0][1] += a0 * bb.y;
            acc[0][2] += a0 * bb.z; acc[0][3] += a0 * bb.w;
            acc[1][0] += a1 * bb.x; acc[1][1] += a1 * bb.y;
            acc[1][2] += a1 * bb.z; acc[1][3] += a1 * bb.w;
        }
        __syncthreads();
    }

    if (z < 2) {
        float* O = (z == 0) ? q : kT;
        #pragma unroll
        for (int i = 0; i < 2; i++) {
            int m = m0 + ty * 2 + i;
            int b = m >> 8, l = m & 255;
            #pragma unroll
            for (int j = 0; j < 4; j++) {
                int n = n0 + tx * 4 + j;
                int h = n >> 6, d = n & 63;
                float val = acc[i][j] + bias[n];
                if (z == 1)
                    O[((b * NH + h) * DQ + d) * NL + l] = val;   // kT
                else
                    O[((b * NH + h) * NL + l) * DQ + d] = val;
            }
        }
    } else {
        int h = blockIdx.x;            // n-tile == head
        int b = m0 >> 8;
        #pragma unroll
        for (int i = 0; i < 2; i++)
            #pragma unroll
            for (int j = 0; j < 4; j++)
                Bs[ty * 2 + i][tx * 4 + j] = acc[i][j] + bias[n0 + tx * 4 + j];
        __syncthreads();

        int r0 = ty * 2, c4 = tx * 4;
        float ur[2][4] = {}, ui[2][4] = {};
        const float* wr = Wre + h * 4096 + c4;
        const float* wi = Wim + h * 4096 + c4;
        #pragma unroll 4
        for (int d = 0; d < 64; d++) {
            float v0 = Bs[r0][d];
            float v1 = Bs[r0 + 1][d];
            float4 wre = *(const float4*)(wr + d * 64);
            float4 wim = *(const float4*)(wi + d * 64);
            ur[0][0] += v0 * wre.x; ur[0][1] += v0 * wre.y;
            ur[0][2] += v0 * wre.z; ur[0][3] += v0 * wre.w;
            ui[0][0] += v0 * wim.x; ui[0][1] += v0 * wim.y;
            ui[0][2] += v0 * wim.z; ui[0][3] += v0 * wim.w;
            ur[1][0] += v1 * wre.x; ur[1][1] += v1 * wre.y;
            ur[1][2] += v1 * wre.z; ur[1][3] += v1 * wre.w;
            ui[1][0] += v1 * wim.x; ui[1][1] += v1 * wim.y;
            ui[1][2] += v1 * wim.z; ui[1][3] += v1 * wim.w;
        }
        #pragma unroll
        for (int i = 0; i < 2; i++) {
            int l = (m0 & 255) + r0 + i;
            float2* up = u + ((size_t)(b * NH + h) * NL + l) * DQ + c4;
            #pragma unroll
            for (int j = 0; j < 4; j++)
                up[j] = make_float2(ur[i][j], ui[i][j]);
        }
    }
}

// ---------------------------------------------------------------------------
// K2: attn prologue (R1-passed, verbatim) + EUNN recurrence (R4-passed body,
// verbatim) in ONE kernel (R4's split cost ~12 us of launch gap).
// THIS ROUND'S FIX: sched_barrier(0) fences after each prefetch-group load
// block. R4's VGPR_Count=32 proved the scheduler sank the register
// double-buffer loads into the serial chain (min-reg heuristic) -> ~217
// idle cy/step of exposed L2 latency. The fence pins program order so the
// waitcnt inserter emits counted vmcnt waits: next group's 8 loads stay in
// flight across the current group's ~900 cy of compute.
// NOTE: no asm "+v" value pins -- those would force vmcnt(0) at the pin.
// ---------------------------------------------------------------------------
__device__ __forceinline__ float dpp_swap1(float x) {  // lane i <- lane i^1
    return __int_as_float(__builtin_amdgcn_mov_dpp(__float_as_int(x), 0xB1, 0xF, 0xF, true));
}
__device__ __forceinline__ float dpp_rol1(float x) {   // lane i <- lane (i+1)%64
    return __int_as_float(__builtin_amdgcn_mov_dpp(__float_as_int(x), 0x134, 0xF, 0xF, true));
}
__device__ __forceinline__ float dpp_ror1(float x) {   // lane i <- lane (i-1)%64
    return __int_as_float(__builtin_amdgcn_mov_dpp(__float_as_int(x), 0x13C, 0xF, 0xF, true));
}

__device__ __forceinline__ v2f mdr(v2f z, float bv) {  // modrelu, exact reference form
    float mm = z.x * z.x + z.y * z.y;
    float m = __builtin_amdgcn_sqrtf(mm);
    float sc = fmaxf(m + bv, 0.f) * __builtin_amdgcn_rcpf(m + 1e-5f);
    v2f s = {sc, sc};
    return z * s;
}

__global__ __launch_bounds__(256, 4) void rnn_kernel(
    const float* __restrict__ q, const float* __restrict__ kT,
    const float* __restrict__ mask, float* __restrict__ attn_o,
    const float2* __restrict__ u,
    const float* __restrict__ theta, const float* __restrict__ phi,
    const float* __restrict__ rnn_bias, float* __restrict__ rnn_out)
{
    int tid  = threadIdx.x;
    int wv   = tid >> 6;          // wave = one q row
    int lane = tid & 63;

    int blk = blockIdx.x;         // 1024: b(1) | h(3) | qg(6)
    int qg  = blk & 63;           // group of 4 q rows
    int h   = (blk >> 6) & 7;
    int b   = blk >> 9;

    __shared__ float qs[256];
    __shared__ float lg[4 * 260];
    __shared__ float redm[4], reds[4];
    __shared__ float arow[4 * 256];

    // ================= attn prologue (R1-passed, verbatim) =================
    float acc[4];
    {
        qs[tid] = q[((size_t)(b * NH + h) * NL + qg * 4) * DQ + tid];
        __syncthreads();

        const float* kp = kT + (size_t)((b * NH + h) * DQ) * NL + tid;
        #pragma unroll
        for (int j = 0; j < 4; j++) acc[j] = 0.f;
        #pragma unroll
        for (int d4 = 0; d4 < 16; d4++) {
            float kv0 = kp[(d4 * 4 + 0) * NL];
            float kv1 = kp[(d4 * 4 + 1) * NL];
            float kv2 = kp[(d4 * 4 + 2) * NL];
            float kv3 = kp[(d4 * 4 + 3) * NL];
            #pragma unroll
            for (int j = 0; j < 4; j++) {
                const float4 qv = *(const float4*)&qs[j * 64 + d4 * 4];
                acc[j] += qv.x * kv0 + qv.y * kv1 + qv.z * kv2 + qv.w * kv3;
            }
        }
        #pragma unroll
        for (int j = 0; j < 4; j++) {
            float mv = mask[(size_t)(b * NL + qg * 4 + j) * NL + tid];
            acc[j] = acc[j] * 0.125f - ((mv == 1.0f) ? INFINITY : mv);
            lg[j * 260 + tid] = acc[j];
        }
        __syncthreads();
        {
            int j = wv;   // one row per wave
            float v0 = lg[j * 260 + lane],       v1 = lg[j * 260 + 64 + lane];
            float v2 = lg[j * 260 + 128 + lane], v3 = lg[j * 260 + 192 + lane];
            float mx = fmaxf(fmaxf(v0, v1), fmaxf(v2, v3));
            #pragma unroll
            for (int o = 32; o; o >>= 1) mx = fmaxf(mx, __shfl_xor(mx, o, 64));
            float s = __expf(v0 - mx) + __expf(v1 - mx) +
                      __expf(v2 - mx) + __expf(v3 - mx);
            #pragma unroll
            for (int o = 32; o; o >>= 1) s += __shfl_xor(s, o, 64);
            if (lane == 0) { redm[j] = mx; reds[j] = s; }
        }
        __syncthreads();
        #pragma unroll
        for (int j = 0; j < 4; j++) {
            float p = __expf(acc[j] - redm[j]) * __builtin_amdgcn_rcpf(reds[j]);
            attn_o[((size_t)(b * NH + h) * NL + qg * 4 + j) * NL + tid] = p;
            arow[j * 256 + tid] = p;
        }
        __syncthreads();
    }

    // ================= EUNN recurrence (R4-passed body, verbatim) ==========
    int qi = qg * 4 + wv;
    int d = lane;
    bool odd = d & 1;

    const float* tb = theta + h * 64;    // (8,2,32): c=0 at [0..31], c=1 at [32..63]
    const float* pb = phi + h * 64;

    int i0 = d >> 1;
    float th0 = tb[i0], ph0 = pb[i0];
    float c0 = cosf(th0), s0 = sinf(th0);
    float W0r = (odd ? s0 : -s0) * cosf(ph0);
    float W0i = -s0 * sinf(ph0);

    int i1 = odd ? (d >> 1) : (((d + 62) & 63) >> 1);
    float th1 = tb[32 + i1], ph1 = pb[32 + i1];
    float c1 = cosf(th1), s1 = sinf(th1);
    float W1r = (odd ? -s1 : s1) * cosf(ph1);
    float W1i = -s1 * sinf(ph1);

    float biasv = rnn_bias[h * 64 + d];

    v2f c0v = {c0, c0}, c1v = {c1, c1};
    v2f W0rV = {W0r, W0r}, W0iN = {-W0i, W0i};
    v2f W1rV = {W1r, W1r}, W1iN = {-W1i, W1i};

    const float* arl = arow + wv * 256;                           // LDS, wave-uniform
    const float2* up = u + (size_t)((b * NH + h) * NL) * DQ + d;  // coalesced

    v2f e = {0.f, 0.f};

    #define RSTEP(a_t, uu) do {                                              \
        v2f atv = {(a_t), (a_t)};                                            \
        v2f uv = {(uu).x, (uu).y};                                           \
        v2f p0;                                                              \
        p0.x = dpp_swap1(e.x); p0.y = dpp_swap1(e.y);                        \
        v2f g = fmav(c0v, e, fmav(W0rV, p0, W0iN * swapv(p0)));              \
        v2f rl, rr;                                                          \
        rl.x = dpp_rol1(g.x); rl.y = dpp_rol1(g.y);                          \
        rr.x = dpp_ror1(g.x); rr.y = dpp_ror1(g.y);                          \
        v2f p1;                                                              \
        p1.x = odd ? rl.x : rr.x;                                            \
        p1.y = odd ? rl.y : rr.y;                                            \
        v2f z = fmav(c1v, g, fmav(W1rV, p1, fmav(W1iN, swapv(p1), atv * uv))); \
        e = mdr(z, biasv);                                                   \
    } while (0)

    // register double-buffer, 8-step groups; sched_barrier(0) pins the loads
    // ahead of the compute so counted vmcnt waits pipeline them.
    float2 U0[8], U1[8];
    float4 a0lo, a0hi, a1lo, a1hi;

    #pragma unroll
    for (int i = 0; i < 8; i++) U0[i] = up[i * 64];
    a0lo = *(const float4*)&arl[0];
    a0hi = *(const float4*)&arl[4];
    __builtin_amdgcn_sched_barrier(0);

    for (int k = 0; k < 16; k++) {            // 16 steps per iteration
        int t1 = k * 16 + 8;
        #pragma unroll
        for (int i = 0; i < 8; i++) U1[i] = up[(t1 + i) * 64];
        a1lo = *(const float4*)&arl[t1];
        a1hi = *(const float4*)&arl[t1 + 4];
        __builtin_amdgcn_sched_barrier(0);

        RSTEP(a0lo.x, U0[0]); RSTEP(a0lo.y, U0[1]);
        RSTEP(a0lo.z, U0[2]); RSTEP(a0lo.w, U0[3]);
        RSTEP(a0hi.x, U0[4]); RSTEP(a0hi.y, U0[5]);
        RSTEP(a0hi.z, U0[6]); RSTEP(a0hi.w, U0[7]);

        if (k < 15) {
            int t2 = k * 16 + 16;
            #pragma unroll
            for (int i = 0; i < 8; i++) U0[i] = up[(t2 + i) * 64];
            a0lo = *(const float4*)&arl[t2];
            a0hi = *(const float4*)&arl[t2 + 4];
        }
        __builtin_amdgcn_sched_barrier(0);

        RSTEP(a1lo.x, U1[0]); RSTEP(a1lo.y, U1[1]);
        RSTEP(a1lo.z, U1[2]); RSTEP(a1lo.w, U1[3]);
        RSTEP(a1hi.x, U1[4]); RSTEP(a1hi.y, U1[5]);
        RSTEP(a1hi.z, U1[6]); RSTEP(a1hi.w, U1[7]);
    }
    #undef RSTEP

    rnn_out[(size_t)(b * NL + qi) * DM + h * DQ + d] = e.x;
}

// ---------------------------------------------------------------------------
// K3: output projection (R16-passed, unchanged). Register double-buffered.
// ---------------------------------------------------------------------------
__global__ __launch_bounds__(256) void out_gemm(
    const float* __restrict__ A, const float* __restrict__ W,
    const float* __restrict__ bias, float* __restrict__ C)
{
    __shared__ float As[32][17];
    __shared__ float Bs[32][68];

    int tid = threadIdx.x;
    int tx = tid & 15, ty = tid >> 4;
    int m0 = blockIdx.y * 16, n0 = blockIdx.x * 64;

    int ar = tid >> 4, ac2 = (tid & 15) * 2;
    int br = tid >> 4, bc4 = (tid & 15) * 4;
    const float* Aptr = A + (m0 + ar) * 512 + ac2;
    const float* Bptr0 = W + br * 512 + n0 + bc4;
    const float* Bptr1 = W + (br + 16) * 512 + n0 + bc4;

    float acc[4] = {};

    float2 aR = *(const float2*)(Aptr);
    float4 bR0 = *(const float4*)(Bptr0);
    float4 bR1 = *(const float4*)(Bptr1);

    for (int k0 = 0; k0 < 512; k0 += 32) {
        As[ac2 + 0][ar] = aR.x; As[ac2 + 1][ar] = aR.y;
        *(float4*)&Bs[br][bc4] = bR0;
        *(float4*)&Bs[br + 16][bc4] = bR1;
        __syncthreads();

        if (k0 + 32 < 512) {
            aR  = *(const float2*)(Aptr + k0 + 32);
            bR0 = *(const float4*)(Bptr0 + (k0 + 32) * 512);
            bR1 = *(const float4*)(Bptr1 + (k0 + 32) * 512);
        }

        #pragma unroll
        for (int kk = 0; kk < 32; kk++) {
            float a = As[kk][ty];
            float4 bb = *(const float4*)&Bs[kk][tx * 4];
            acc[0] += a * bb.x; acc[1] += a * bb.y;
            acc[2] += a * bb.z; acc[3] += a * bb.w;
        }
        __syncthreads();
    }

    int m = m0 + ty;
    #pragma unroll
    for (int j = 0; j < 4; j++) {
        int n = n0 + tx * 4 + j;
        C[m * 512 + n] = acc[j] + bias[n];
    }
}

// ---------------------------------------------------------------------------
extern "C" void kernel_launch(void* const* d_in, const int* in_sizes, int n_in,
                              void* d_out, int out_size, void* d_ws, size_t ws_size,
                              hipStream_t stream)
{
    const float* x_q  = (const float*)d_in[0];
    const float* x_k  = (const float*)d_in[1];
    const float* x_v  = (const float*)d_in[2];
    const float* mask = (const float*)d_in[3];
    const float* Wq   = (const float*)d_in[4];
    const float* bq   = (const float*)d_in[5];
    const float* Wk   = (const float*)d_in[6];
    const float* bk   = (const float*)d_in[7];
    const float* Wv   = (const float*)d_in[8];
    const float* bv   = (const float*)d_in[9];
    const float* Wo   = (const float*)d_in[10];
    const float* bo   = (const float*)d_in[11];
    const float* theta= (const float*)d_in[12];
    const float* phi  = (const float*)d_in[13];
    const float* Wre  = (const float*)d_in[14];
    const float* Wim  = (const float*)d_in[15];
    const float* rb   = (const float*)d_in[16];

    float* ws = (float*)d_ws;
    float*  q_ws    = ws;                       // 262144 f
    float*  kT_ws   = ws + 262144;              // 262144 f (b,h,d,t)
    float2* u_ws    = (float2*)(ws + 524288);   // 262144 float2
    float*  rnn_o   = ws + 1048576;             // 262144 f

    float* out_o  = (float*)d_out;              // (2,256,512)
    float* attn_o = out_o + NB * NL * DM;       // (2,8,256,256)

    qkv_gemm<<<dim3(8, 16, 3), 256, 0, stream>>>(
        x_q, x_k, x_v, Wq, Wk, Wv, bq, bk, bv, Wre, Wim,
        q_ws, kT_ws, u_ws);

    rnn_kernel<<<dim3(1024), 256, 0, stream>>>(
        q_ws, kT_ws, mask, attn_o, u_ws, theta, phi, rb, rnn_o);

    out_gemm<<<dim3(8, 32), 256, 0, stream>>>(rnn_o, Wo, bo, out_o);
}